// Round 5
// baseline (203.526 us; speedup 1.0000x reference)
//
#include <hip/hip_runtime.h>
#include <hip/hip_bf16.h>

// AttentionHeadRankFour: B=8, X=8, S=1024, D_IN=512, D_OUT=64
// out = softmax_causal( (Xq Wq)(Xk Wk)^T / sqrt(S) ) (Xv Wv)
//
// Pass 0: wprep converts W (fp32) -> bf16 fragment-ordered (q_w pre-scaled 1/32).
// Pass 1: proj v5 — canonical LDS-staged GEMM. Coalesced A loads -> bf16 ->
//         XOR-swizzled LDS double buffer; W frags in LDS; 16x16x32 MFMA.
// Pass 2: flash attention, bf16 MFMA, online softmax.

typedef short  short8 __attribute__((ext_vector_type(8)));
typedef float  f32x4  __attribute__((ext_vector_type(4)));

#define DIN   512
#define DOUT  64
#define SEQ   1024
#define NROWS 65536   // 8*8*1024

__device__ __forceinline__ unsigned short f2bf(float f) {
    unsigned int u = __float_as_uint(f);
    u += 0x7FFF + ((u >> 16) & 1);   // RNE
    return (unsigned short)(u >> 16);
}

// ---------------------------------------------------------------------------
// Weight prep: grid (16,3), 256 thr. Wfrag[mode][kk][nt][lane][8] bf16,
// element = W[kk*32 + lg*8 + j][nt*16 + lr]; mode 2 pre-scaled by 1/32.
// ---------------------------------------------------------------------------
__global__ __launch_bounds__(256)
void wprep_kernel(const float* __restrict__ k_w, const float* __restrict__ v_w,
                  const float* __restrict__ q_w, unsigned short* __restrict__ Wfrag)
{
    const int mode = blockIdx.y;
    const float* w = (mode == 0) ? k_w : (mode == 1) ? v_w : q_w;
    const float sc = (mode == 2) ? 0.03125f : 1.0f;
    unsigned short* outp = Wfrag + (size_t)mode * 32768;

    const int s  = blockIdx.x * 256 + threadIdx.x;   // (kk,nt,lane) slot
    const int l  = s & 63;
    const int nt = (s >> 6) & 3;
    const int kk = s >> 8;
    const int lr = l & 15, lg = l >> 4;
    short8 frag;
    #pragma unroll
    for (int j = 0; j < 8; ++j)
        frag[j] = (short)f2bf(w[(kk * 32 + lg * 8 + j) * 64 + nt * 16 + lr] * sc);
    *(short8*)&outp[(size_t)s * 8] = frag;
}

// ---------------------------------------------------------------------------
// proj v5. Grid (512, 3), 512 thr = 8 waves. Block owns 128 rows x K=512.
// A staged per 128-col K-chunk: coalesced fp32 loads (512B contiguous/wave
// half), f2bf, ds_write with XOR swizzle (addr ^= (row&7)<<4). Double buffer.
// Wave w computes rows [wid*16, +16) x all 64 cols from LDS fragments.
// ---------------------------------------------------------------------------
__global__ __launch_bounds__(512, 2)
void proj_kernel(const float* __restrict__ k_in, const float* __restrict__ v_in,
                 const float* __restrict__ q_in,
                 const unsigned short* __restrict__ Wfrag,
                 unsigned short* __restrict__ Kb, unsigned short* __restrict__ Vt,
                 unsigned short* __restrict__ Qb)
{
    const int mode = blockIdx.y;
    const float* in = (mode == 0) ? k_in : (mode == 1) ? v_in : q_in;
    const unsigned short* wf = Wfrag + (size_t)mode * 32768;

    __shared__ __align__(16) unsigned short Wlds[32768];       // 64 KB
    __shared__ __align__(16) unsigned short Alds[2][16384];    // 2 x 32 KB

    const int tid = threadIdx.x;
    const int wid = tid >> 6;
    const int l   = tid & 63;
    const int lr  = l & 15;
    const int lg  = l >> 4;
    const int r0  = blockIdx.x * 128;

    // Staging geometry: thread t covers rows (t>>5) + 16i, float4 col (t&31).
    const int srow = tid >> 5;
    const int scol = tid & 31;
    const float* sbase = in + (size_t)(r0 + srow) * DIN + scol * 4;

    float4 rA[8], rB[8];

    #define LOADC(r, c)                                                        \
        { _Pragma("unroll")                                                    \
          for (int i = 0; i < 8; ++i)                                          \
              r[i] = *(const float4*)(sbase + (size_t)i * 16 * DIN + (c) * 128); }

    #define WRITEC(buf, r)                                                     \
        { _Pragma("unroll")                                                    \
          for (int i = 0; i < 8; ++i) {                                        \
              const int row = srow + i * 16;                                   \
              ushort4 pk;                                                      \
              pk.x = f2bf(r[i].x); pk.y = f2bf(r[i].y);                        \
              pk.z = f2bf(r[i].z); pk.w = f2bf(r[i].w);                        \
              *(ushort4*)((char*)&Alds[buf][0] +                               \
                  ((row * 256 + scol * 8) ^ ((row & 7) << 4))) = pk;           \
          } }

    const int arow  = wid * 16 + lr;
    const int abase = arow * 256 + lg * 16;     // byte offset, + kk*64
    const int aswz  = (arow & 7) << 4;

    f32x4 acc[4];
    #pragma unroll
    for (int nt = 0; nt < 4; ++nt)
        #pragma unroll
        for (int i = 0; i < 4; ++i) acc[nt][i] = 0.f;

    #define COMPUTEC(buf, c)                                                   \
        { _Pragma("unroll")                                                    \
          for (int k = 0; k < 4; ++k) {                                        \
              const short8 af = *(const short8*)((const char*)&Alds[buf][0] +  \
                                  ((abase + k * 64) ^ aswz));                  \
              const int kk = (c) * 4 + k;                                      \
              _Pragma("unroll")                                                \
              for (int nt = 0; nt < 4; ++nt) {                                 \
                  const short8 bf = *(const short8*)&Wlds[((kk * 4 + nt) * 64 + l) * 8]; \
                  acc[nt] = __builtin_amdgcn_mfma_f32_16x16x32_bf16(af, bf, acc[nt], 0, 0, 0); \
              }                                                                \
          } }

    // Prologue: A-chunk loads first (HBM long-pole), then W stage, then write c0.
    LOADC(rA, 0);
    LOADC(rB, 1);
    #pragma unroll
    for (int i = 0; i < 8; ++i)
        *(short8*)&Wlds[(i * 512 + tid) * 8] = *(const short8*)&wf[(size_t)(i * 512 + tid) * 8];
    WRITEC(0, rA);
    __syncthreads();

    // c=0
    LOADC(rA, 2);
    WRITEC(1, rB);
    COMPUTEC(0, 0);
    __syncthreads();
    // c=1
    LOADC(rB, 3);
    WRITEC(0, rA);
    COMPUTEC(1, 1);
    __syncthreads();
    // c=2
    WRITEC(1, rB);
    COMPUTEC(0, 2);
    __syncthreads();
    // c=3
    COMPUTEC(1, 3);

    // Epilogue. C frag: col = lr, row = lg*4 + i within wave tile (base wid*16).
    if (mode == 1) {
        const int grow = r0 + wid * 16 + lg * 4;
        const int bx = grow >> 10, s = grow & 1023;
        #pragma unroll
        for (int nt = 0; nt < 4; ++nt) {
            ushort4 pk;
            pk.x = f2bf(acc[nt][0]); pk.y = f2bf(acc[nt][1]);
            pk.z = f2bf(acc[nt][2]); pk.w = f2bf(acc[nt][3]);
            *(ushort4*)&Vt[(size_t)bx * 65536 + (size_t)(nt * 16 + lr) * 1024 + s] = pk;
        }
    } else {
        unsigned short* outp = (mode == 0) ? Kb : Qb;
        const int rbase = r0 + wid * 16 + lg * 4;
        #pragma unroll
        for (int nt = 0; nt < 4; ++nt)
            #pragma unroll
            for (int i = 0; i < 4; ++i)
                outp[(size_t)(rbase + i) * 64 + nt * 16 + lr] = f2bf(acc[nt][i]);
    }
    #undef LOADC
    #undef WRITEC
    #undef COMPUTEC
}

// ---------------------------------------------------------------------------
// Flash attention, causal. Grid: (16 q-blocks, 64 bx heads). 256 thr = 4 waves.
// Wave w owns q rows [qblk*64 + w*16, +16). KB=64 keys per chunk.
// ---------------------------------------------------------------------------
__global__ __launch_bounds__(256)
void attn_kernel(const unsigned short* __restrict__ Qb,
                 const unsigned short* __restrict__ Kb,
                 const unsigned short* __restrict__ Vt,
                 float* __restrict__ out)
{
    __shared__ __align__(16) unsigned short Plds[4][16][72];  // per-wave P tile, padded

    const int tid  = threadIdx.x;
    const int wid  = tid >> 6;
    const int l    = tid & 63;
    const int lr   = l & 15;
    const int lg   = l >> 4;
    const int qblk = 15 - (int)blockIdx.x;       // big blocks first
    const int bx   = blockIdx.y;
    const int qw0  = qblk * 64 + wid * 16;

    const unsigned short* Qp = Qb + (size_t)bx * 65536;
    const unsigned short* Kp = Kb + (size_t)bx * 65536;
    const unsigned short* Vp = Vt + (size_t)bx * 65536;   // [d][s]

    const short8 qa0 = *(const short8*)&Qp[(size_t)(qw0 + lr) * 64 + lg * 8];
    const short8 qa1 = *(const short8*)&Qp[(size_t)(qw0 + lr) * 64 + 32 + lg * 8];

    float m[4], lsum[4];
    f32x4 acc[4];
    #pragma unroll
    for (int i = 0; i < 4; ++i) { m[i] = -INFINITY; lsum[i] = 0.f; }
    #pragma unroll
    for (int dt = 0; dt < 4; ++dt)
        #pragma unroll
        for (int i = 0; i < 4; ++i) acc[dt][i] = 0.f;

    const int qrow = qw0 + lg * 4;   // + i

    for (int kb = 0; kb <= qw0; kb += 64) {
        // ---- scores: 4 tiles of 16 keys ----
        f32x4 s[4];
        #pragma unroll
        for (int kt = 0; kt < 4; ++kt) {
            const int kbase = kb + kt * 16;
            if (kbase <= qw0 + 15) {           // wave-uniform
                const short8 k0 = *(const short8*)&Kp[(size_t)(kbase + lr) * 64 + lg * 8];
                const short8 k1 = *(const short8*)&Kp[(size_t)(kbase + lr) * 64 + 32 + lg * 8];
                f32x4 t;
                #pragma unroll
                for (int i = 0; i < 4; ++i) t[i] = 0.f;
                t = __builtin_amdgcn_mfma_f32_16x16x32_bf16(qa0, k0, t, 0, 0, 0);
                t = __builtin_amdgcn_mfma_f32_16x16x32_bf16(qa1, k1, t, 0, 0, 0);
                const int kcol = kbase + lr;
                #pragma unroll
                for (int i = 0; i < 4; ++i)
                    s[kt][i] = (kcol <= qrow + i) ? t[i] : -INFINITY;
            } else {
                #pragma unroll
                for (int i = 0; i < 4; ++i) s[kt][i] = -INFINITY;
            }
        }
        // ---- online softmax ----
        float tm[4];
        #pragma unroll
        for (int i = 0; i < 4; ++i)
            tm[i] = fmaxf(fmaxf(s[0][i], s[1][i]), fmaxf(s[2][i], s[3][i]));
        #pragma unroll
        for (int d = 1; d < 16; d <<= 1)
            #pragma unroll
            for (int i = 0; i < 4; ++i)
                tm[i] = fmaxf(tm[i], __shfl_xor(tm[i], d));

        float rs[4], ps[4];
        #pragma unroll
        for (int i = 0; i < 4; ++i) {
            const float mn = fmaxf(m[i], tm[i]);
            rs[i] = __expf(m[i] - mn);
            m[i] = mn;
            ps[i] = 0.f;
        }
        #pragma unroll
        for (int kt = 0; kt < 4; ++kt)
            #pragma unroll
            for (int i = 0; i < 4; ++i) {
                const float p = __expf(s[kt][i] - m[i]);   // masked -> 0
                ps[i] += p;
                Plds[wid][lg * 4 + i][kt * 16 + lr] = f2bf(p);
            }
        #pragma unroll
        for (int d = 1; d < 16; d <<= 1)
            #pragma unroll
            for (int i = 0; i < 4; ++i) ps[i] += __shfl_xor(ps[i], d);
        #pragma unroll
        for (int i = 0; i < 4; ++i) lsum[i] = lsum[i] * rs[i] + ps[i];
        #pragma unroll
        for (int dt = 0; dt < 4; ++dt)
            #pragma unroll
            for (int i = 0; i < 4; ++i) acc[dt][i] *= rs[i];

        // wave-private LDS write -> read (same wave); drain LDS then re-read
        asm volatile("s_waitcnt lgkmcnt(0)" ::: "memory");
        __builtin_amdgcn_sched_barrier(0);

        // ---- PV ----
        const int cmax = (kb + 32 <= qw0 + 15) ? 2 : 1;
        for (int c = 0; c < cmax; ++c) {
            const short8 pa = *(const short8*)&Plds[wid][lr][c * 32 + lg * 8];
            #pragma unroll
            for (int dt = 0; dt < 4; ++dt) {
                const short8 vb = *(const short8*)&Vp[(size_t)(dt * 16 + lr) * 1024 + kb + c * 32 + lg * 8];
                acc[dt] = __builtin_amdgcn_mfma_f32_16x16x32_bf16(pa, vb, acc[dt], 0, 0, 0);
            }
        }
        asm volatile("s_waitcnt lgkmcnt(0)" ::: "memory");
    }

    // ---- epilogue ----
    float inv[4];
    #pragma unroll
    for (int i = 0; i < 4; ++i) inv[i] = 1.0f / lsum[i];
    const size_t orow = (size_t)bx * 1024 + qw0;
    #pragma unroll
    for (int dt = 0; dt < 4; ++dt)
        #pragma unroll
        for (int i = 0; i < 4; ++i)
            out[(orow + lg * 4 + i) * 64 + dt * 16 + lr] = acc[dt][i] * inv[i];
}

extern "C" void kernel_launch(void* const* d_in, const int* in_sizes, int n_in,
                              void* d_out, int out_size, void* d_ws, size_t ws_size,
                              hipStream_t stream) {
    const float* k_in = (const float*)d_in[0];
    const float* v_in = (const float*)d_in[1];
    const float* q_in = (const float*)d_in[2];
    const float* k_w  = (const float*)d_in[3];
    const float* v_w  = (const float*)d_in[4];
    const float* q_w  = (const float*)d_in[5];

    unsigned short* Kb    = (unsigned short*)d_ws;              // [65536][64] bf16
    unsigned short* Vt    = Kb + (size_t)NROWS * 64;            // [64][64][1024] bf16
    unsigned short* Qb    = Vt + (size_t)NROWS * 64;            // [65536][64] bf16 (scale in W)
    unsigned short* Wfrag = Qb + (size_t)NROWS * 64;            // 3 x 32768 bf16 fragments

    wprep_kernel<<<dim3(16, 3), 256, 0, stream>>>(k_w, v_w, q_w, Wfrag);
    proj_kernel<<<dim3(512, 3), 512, 0, stream>>>(
        k_in, v_in, q_in, Wfrag, Kb, Vt, Qb);
    attn_kernel<<<dim3(16, 64), 256, 0, stream>>>(Qb, Kb, Vt, (float*)d_out);
}